// Round 1
// baseline (158.416 us; speedup 1.0000x reference)
//
#include <hip/hip_runtime.h>
#include <math.h>

#define NB 2
#define NA 128
#define KD 32
#define LS 33            // LDS row stride (bank-conflict pad)
#define BN (NB*NA)       // 256 agents total

// Static device scratch (graph-capture-safe; fully rewritten every launch).
__device__ __align__(16) float g_Q[BN*KD*KD];   // E^T (Sig+eps)^-1 E
__device__ __align__(16) float g_T[BN*KD*KD];   // E^T (Sig+eps) E
__device__ __align__(16) float g_E[BN*KD*KD];   // expm(X)
__device__ __align__(16) float g_v[BN*KD];      // E^T mu
__device__ __align__(16) float g_ld[BN];        // logdet(Sig+eps)

// ---------------- Kernel 1: per-agent factorizations ----------------
__global__ __launch_bounds__(256) void agent_kernel(
    const float* __restrict__ mu_q, const float* __restrict__ sigma_q,
    const float* __restrict__ phi, const float* __restrict__ gen) {
  const int g = blockIdx.x;          // agent index b*NA + n
  const int tid = threadIdx.x;
  __shared__ __align__(16) float sM[KD*LS];   // Sigma + eps I
  __shared__ __align__(16) float sE[KD*LS];   // exp accumulator
  __shared__ __align__(16) float sX[KD*LS];   // scaled X, later W = Linv*E
  __shared__ __align__(16) float sT1[KD*LS];
  __shared__ __align__(16) float sT2[KD*LS];
  __shared__ __align__(16) float sL[KD*LS];   // Cholesky L
  __shared__ __align__(16) float sLi[KD*LS];  // L^-1
  __shared__ float smu[KD];
  __shared__ float sphi[3];
  __shared__ float snrm;

  const int e0 = tid * 4;
  const int r0 = e0 >> 5;
  const int c0 = e0 & 31;            // 4 consecutive columns in row r0

  if (tid == 0) snrm = 0.f;
  if (tid < 3) sphi[tid] = phi[g*3 + tid];
  if (tid < KD) smu[tid] = mu_q[g*KD + tid];
  __syncthreads();

  const float p0 = sphi[0], p1 = sphi[1], p2 = sphi[2];
  float nrm = 0.f;
  #pragma unroll
  for (int m = 0; m < 4; ++m) {
    const int e = e0 + m, r = r0, c = c0 + m;
    const float x = p0*gen[e] + p1*gen[1024 + e] + p2*gen[2048 + e];
    sX[r*LS + c] = x;
    nrm += x*x;
    sM[r*LS + c] = sigma_q[(size_t)g*1024 + e] + (r == c ? 1e-8f : 0.f);
  }
  #pragma unroll
  for (int o = 1; o < 64; o <<= 1) nrm += __shfl_xor(nrm, o);
  if ((tid & 63) == 0) atomicAdd(&snrm, nrm);
  __syncthreads();

  // scaling-and-squaring: bring Frobenius norm <= 0.25
  const float anorm = sqrtf(snrm);
  int s = 0;
  if (anorm > 0.25f) {
    s = (int)ceilf(log2f(anorm * 4.0f));
    s = max(0, min(s, 24));
  }
  const float scl = exp2f((float)(-s));
  #pragma unroll
  for (int m = 0; m < 4; ++m) {
    const int r = r0, c = c0 + m;
    const float x = sX[r*LS + c] * scl;
    sX[r*LS + c] = x;
    sE[r*LS + c] = x + (r == c ? 1.f : 0.f);
    sT1[r*LS + c] = x;
  }
  __syncthreads();

  // Taylor series: E = I + Xs + Xs^2/2! + ... + Xs^12/12!
  float* cur = sT1;
  float* nxt = sT2;
  for (int kk = 2; kk <= 12; ++kk) {
    const float inv = 1.0f / (float)kk;
    float acc[4] = {0.f, 0.f, 0.f, 0.f};
    for (int q = 0; q < KD; ++q) {
      const float av = cur[r0*LS + q];
      #pragma unroll
      for (int m = 0; m < 4; ++m) acc[m] += av * sX[q*LS + c0 + m];
    }
    #pragma unroll
    for (int m = 0; m < 4; ++m) {
      const float t = acc[m] * inv;
      nxt[r0*LS + c0 + m] = t;
      sE[r0*LS + c0 + m] += t;
    }
    __syncthreads();
    float* tp = cur; cur = nxt; nxt = tp;
  }

  // squarings: E <- E*E, s times (ping-pong sE <-> sT1)
  float* pe = sE;
  float* sq = sT1;
  for (int t = 0; t < s; ++t) {
    float acc[4] = {0.f, 0.f, 0.f, 0.f};
    for (int q = 0; q < KD; ++q) {
      const float av = pe[r0*LS + q];
      #pragma unroll
      for (int m = 0; m < 4; ++m) acc[m] += av * pe[q*LS + c0 + m];
    }
    #pragma unroll
    for (int m = 0; m < 4; ++m) sq[r0*LS + c0 + m] = acc[m];
    __syncthreads();
    float* tp = pe; pe = sq; sq = tp;
  }

  // Cholesky of sM -> sL, logdet, and L^-1 -> sLi   (wave 0, lanes 0..31)
  if (tid < KD) {
    const int i = tid;
    for (int j = 0; j < KD; ++j) {
      float dot = 0.f;
      for (int q = 0; q < j; ++q) dot += sL[i*LS + q] * sL[j*LS + q];
      const float val = sM[i*LS + j] - dot;
      const float sqv = sqrtf(val);
      const float dj = __shfl(sqv, j);
      float w;
      if (i == j) w = dj;
      else if (i > j) w = val / dj;
      else w = 0.f;
      sL[i*LS + j] = w;
    }
    float ld = 2.0f * logf(sL[i*LS + i]);
    #pragma unroll
    for (int o = 1; o < 32; o <<= 1) ld += __shfl_xor(ld, o);
    if (i == 0) g_ld[g] = ld;

    // forward-substitute column c of L^-1
    const int c = tid;
    for (int r = 0; r < KD; ++r) {
      if (r >= c) {
        float acc = (r == c) ? 1.f : 0.f;
        for (int q = c; q < r; ++q) acc -= sL[r*LS + q] * sLi[q*LS + c];
        sLi[r*LS + c] = acc / sL[r*LS + r];
      } else {
        sLi[r*LS + c] = 0.f;
      }
    }
  }
  __syncthreads();

  // W = Linv * E  -> sX (Xs no longer needed)
  {
    float acc[4] = {0.f, 0.f, 0.f, 0.f};
    for (int q = 0; q < KD; ++q) {
      const float av = sLi[r0*LS + q];
      #pragma unroll
      for (int m = 0; m < 4; ++m) acc[m] += av * pe[q*LS + c0 + m];
    }
    __syncthreads();
    #pragma unroll
    for (int m = 0; m < 4; ++m) sX[r0*LS + c0 + m] = acc[m];
  }
  __syncthreads();

  // Q = W^T W -> global ; ME = M*E -> sT2
  {
    float acc[4]  = {0.f, 0.f, 0.f, 0.f};
    float acc2[4] = {0.f, 0.f, 0.f, 0.f};
    for (int q = 0; q < KD; ++q) {
      const float wv = sX[q*LS + r0];
      const float mv = sM[r0*LS + q];
      #pragma unroll
      for (int m = 0; m < 4; ++m) {
        acc[m]  += wv * sX[q*LS + c0 + m];
        acc2[m] += mv * pe[q*LS + c0 + m];
      }
    }
    #pragma unroll
    for (int m = 0; m < 4; ++m) {
      g_Q[(size_t)g*1024 + r0*KD + c0 + m] = acc[m];
      sT2[r0*LS + c0 + m] = acc2[m];
    }
  }
  __syncthreads();

  // T = E^T * ME -> global ; copy E -> global ; v = E^T mu
  {
    float acc[4] = {0.f, 0.f, 0.f, 0.f};
    for (int q = 0; q < KD; ++q) {
      const float ev = pe[q*LS + r0];
      #pragma unroll
      for (int m = 0; m < 4; ++m) acc[m] += ev * sT2[q*LS + c0 + m];
    }
    #pragma unroll
    for (int m = 0; m < 4; ++m) {
      g_T[(size_t)g*1024 + r0*KD + c0 + m] = acc[m];
      g_E[(size_t)g*1024 + r0*KD + c0 + m] = pe[r0*LS + c0 + m];
    }
  }
  if (tid < KD) {
    float acc = 0.f;
    for (int q = 0; q < KD; ++q) acc += pe[q*LS + tid] * smu[q];
    g_v[g*KD + tid] = acc;
  }
}

// ---------------- Kernel 2: pairwise KL + softmax + aggregate ----------------
__global__ __launch_bounds__(256) void pair_kernel(float* __restrict__ out) {
  const int g = blockIdx.x;          // query agent b*NA + i
  const int b = g >> 7;
  const int i = g & (NA - 1);
  const int tid = threadIdx.x;
  __shared__ __align__(16) float sT[KD*KD];
  __shared__ __align__(16) float sv[NA*KD];
  __shared__ float sld[NA];
  __shared__ float skl[NA];
  __shared__ float sbeta[NA];
  __shared__ float sred[256];
  __shared__ float spart[8*KD];
  __shared__ float sw[KD];

  {
    const float4* src = (const float4*)(g_T + (size_t)g*1024);
    ((float4*)sT)[tid] = src[tid];
    const float4* vsrc = (const float4*)(g_v + (size_t)b*NA*KD);
    for (int m = tid; m < NA*KD/4; m += 256) ((float4*)sv)[m] = vsrc[m];
    if (tid < NA) sld[tid] = g_ld[b*NA + tid];
  }
  __syncthreads();

  const float ldi = sld[i];
  const int lane = tid & 63;
  const int wave = tid >> 6;
  const int k = lane >> 1;           // row of Q owned by this lane
  const int l0 = (lane & 1) * 16;    // half-row offset
  const float vik = sv[i*KD + k];

  for (int j = wave; j < NA; j += 4) {
    const float* Qj = g_Q + (size_t)(b*NA + j)*1024 + k*KD + l0;
    const float* Ti = sT + k*KD + l0;
    const float* vj = sv + j*KD + l0;
    const float* vi = sv + i*KD + l0;
    const float dk = sv[j*KD + k] - vik;
    float tr = 0.f, qd = 0.f;
    #pragma unroll
    for (int m = 0; m < 16; ++m) {
      const float q = Qj[m];
      tr += q * Ti[m];
      qd += q * (vj[m] - vi[m]);
    }
    qd *= dk;
    #pragma unroll
    for (int o = 1; o < 64; o <<= 1) {
      tr += __shfl_xor(tr, o);
      qd += __shfl_xor(qd, o);
    }
    if (lane == 0)
      skl[j] = fmaxf(0.5f * (tr + qd - (float)KD + sld[j] - ldi), 0.f);
  }
  __syncthreads();

  // softmax over j (-kl), then beta = (p + 1e-8)/(1 + 128e-8)
  sred[tid] = (tid < NA) ? -skl[tid] : -3.0e38f;
  __syncthreads();
  for (int o = 128; o > 0; o >>= 1) {
    if (tid < o) sred[tid] = fmaxf(sred[tid], sred[tid + o]);
    __syncthreads();
  }
  const float mx = sred[0];
  __syncthreads();
  const float p = (tid < NA) ? expf(-skl[tid] - mx) : 0.f;
  sred[tid] = p;
  __syncthreads();
  for (int o = 128; o > 0; o >>= 1) {
    if (tid < o) sred[tid] += sred[tid + o];
    __syncthreads();
  }
  const float S = sred[0];
  if (tid < NA) sbeta[tid] = (p / S + 1e-8f) * (1.0f / (1.0f + 128.0f * 1e-8f));
  __syncthreads();

  // w = sum_j beta_j v_j   (8 j-chunks x 32 components)
  {
    const int c = tid >> 5, kk = tid & 31;
    float acc = 0.f;
    for (int j = c*16; j < c*16 + 16; ++j) acc += sbeta[j] * sv[j*KD + kk];
    spart[c*KD + kk] = acc;
  }
  __syncthreads();
  if (tid < KD) {
    float w = 0.f;
    #pragma unroll
    for (int c2 = 0; c2 < 8; ++c2) w += spart[c2*KD + tid];
    sw[tid] = w;
  }
  __syncthreads();
  // out_i = E_i * w
  if (tid < KD) {
    const float* Ei = g_E + (size_t)g*1024 + tid*KD;
    float acc = 0.f;
    for (int l = 0; l < KD; ++l) acc += Ei[l] * sw[l];
    out[g*KD + tid] = acc;
  }
}

extern "C" void kernel_launch(void* const* d_in, const int* in_sizes, int n_in,
                              void* d_out, int out_size, void* d_ws, size_t ws_size,
                              hipStream_t stream) {
  (void)in_sizes; (void)n_in; (void)out_size; (void)d_ws; (void)ws_size;
  const float* mu_q    = (const float*)d_in[0];
  const float* sigma_q = (const float*)d_in[1];
  const float* phi     = (const float*)d_in[2];
  const float* gen     = (const float*)d_in[3];
  float* out = (float*)d_out;
  hipLaunchKernelGGL(agent_kernel, dim3(BN), dim3(256), 0, stream,
                     mu_q, sigma_q, phi, gen);
  hipLaunchKernelGGL(pair_kernel, dim3(BN), dim3(256), 0, stream, out);
}

// Round 2
// 113.773 us; speedup vs baseline: 1.3924x; 1.3924x over previous
//
#include <hip/hip_runtime.h>
#include <math.h>

#define NB 2
#define NA 128
#define KD 32
#define LS 36            // LDS row stride: 16B-aligned float4s, conflict-free
#define BN (NB*NA)       // 256 agents total
#define EPSV 1e-8f

// Static device scratch (graph-capture-safe; fully rewritten every launch).
__device__ __align__(16) float g_Q[BN*KD*KD];   // E^T (Sig+eps)^-1 E
__device__ __align__(16) float g_T[BN*KD*KD];   // E^T (Sig+eps) E
__device__ __align__(16) float g_E[BN*KD*KD];   // expm(X)
__device__ __align__(16) float g_v[BN*KD];      // E^T mu
__device__ __align__(16) float g_ld[BN];        // logdet(Sig+eps)

// acc[m] += sum_q A[r0][q] * B[q][c0+m]   (32x32, LS-strided LDS tiles)
__device__ __forceinline__ void mm4(const float* A, const float* B,
                                    int r0, int c0, float acc[4]) {
  #pragma unroll
  for (int q4 = 0; q4 < KD; q4 += 4) {
    const float4 a4 = *(const float4*)&A[r0*LS + q4];
    const float ar[4] = {a4.x, a4.y, a4.z, a4.w};
    #pragma unroll
    for (int u = 0; u < 4; ++u) {
      const float4 b4 = *(const float4*)&B[(q4+u)*LS + c0];
      acc[0] += ar[u]*b4.x; acc[1] += ar[u]*b4.y;
      acc[2] += ar[u]*b4.z; acc[3] += ar[u]*b4.w;
    }
  }
}

// ---------------- Kernel 1: per-agent factorizations ----------------
__global__ __launch_bounds__(256) void agent_kernel(
    const float* __restrict__ mu_q, const float* __restrict__ sigma_q,
    const float* __restrict__ phi, const float* __restrict__ gen) {
  const int g = blockIdx.x;
  const int tid = threadIdx.x;
  __shared__ __align__(16) float sM[KD*LS];
  __shared__ __align__(16) float sX[KD*LS];   // unscaled X
  __shared__ __align__(16) float sX2[KD*LS];  // (Xs)^2
  __shared__ __align__(16) float sX4[KD*LS];  // (Xs)^4
  __shared__ __align__(16) float sB1[KD*LS];  // C1(Xs), later ME
  __shared__ __align__(16) float sB2[KD*LS];  // C2(Xs), later ME
  __shared__ __align__(16) float sE[KD*LS];
  __shared__ __align__(16) float sF[KD*LS];   // X8, then squaring ping-pong
  __shared__ __align__(16) float sW[KD*LS];   // W = L^-1 E
  __shared__ float snrm;

  const int e0 = tid * 4;
  const int r0 = e0 >> 5;
  const int c0 = e0 & 31;

  // ---- build X (unscaled) + M, Frobenius norm ----
  const float p0 = phi[g*3+0], p1 = phi[g*3+1], p2 = phi[g*3+2];
  if (tid == 0) snrm = 0.f;
  float nrm = 0.f;
  {
    const float* g0p = gen + e0;
    const float* g1p = gen + 1024 + e0;
    const float* g2p = gen + 2048 + e0;
    const float4 sg = *(const float4*)(sigma_q + (size_t)g*1024 + e0);
    const float sgv[4] = {sg.x, sg.y, sg.z, sg.w};
    #pragma unroll
    for (int m = 0; m < 4; ++m) {
      const float x = p0*g0p[m] + p1*g1p[m] + p2*g2p[m];
      sX[r0*LS + c0 + m] = x;
      nrm += x*x;
      sM[r0*LS + c0 + m] = sgv[m] + ((r0 == c0 + m) ? EPSV : 0.f);
    }
  }
  __syncthreads();                       // snrm init + LDS visible
  #pragma unroll
  for (int o = 1; o < 64; o <<= 1) nrm += __shfl_xor(nrm, o);
  if ((tid & 63) == 0) atomicAdd(&snrm, nrm);
  __syncthreads();

  const float anorm = sqrtf(snrm);
  int s = 0;
  if (anorm > 1.f) { s = (int)ceilf(log2f(anorm)); s = min(s, 15); }
  const float sc1 = exp2f((float)(-s));  // Xs = sc1 * X
  const float sc2 = sc1*sc1;

  // Taylor coeffs 1/k!
  const float C4 = 1.f/24.f,    C5 = 1.f/120.f,     C6 = 1.f/720.f,     C7 = 1.f/5040.f;
  const float C8 = 1.f/40320.f, C9 = 1.f/362880.f, C10 = 1.f/3628800.f, C11 = 1.f/39916800.f;

  // Phase A: X2s = sc2 * (Xu*Xu)
  {
    float a2[4] = {0.f,0.f,0.f,0.f};
    mm4(sX, sX, r0, c0, a2);
    #pragma unroll
    for (int m = 0; m < 4; ++m) sX2[r0*LS + c0 + m] = a2[m]*sc2;
  }
  __syncthreads();

  // Phase B: X3s = sc1*(X2s*Xu), X4s = X2s*X2s; fold C1/C2 elementwise
  float x3[4];
  {
    float a3[4] = {0.f,0.f,0.f,0.f}, a4[4] = {0.f,0.f,0.f,0.f};
    mm4(sX2, sX, r0, c0, a3);
    mm4(sX2, sX2, r0, c0, a4);
    #pragma unroll
    for (int m = 0; m < 4; ++m) {
      x3[m] = a3[m]*sc1;
      const float dlt = (r0 == c0 + m) ? 1.f : 0.f;
      const float xo  = sX[r0*LS + c0 + m]*sc1;  // Xs element
      const float x2o = sX2[r0*LS + c0 + m];
      sX4[r0*LS + c0 + m] = a4[m];
      sB1[r0*LS + c0 + m] = C4*dlt + C5*xo + C6*x2o + C7*x3[m];
      sB2[r0*LS + c0 + m] = C8*dlt + C9*xo + C10*x2o + C11*x3[m];
    }
  }
  __syncthreads();

  // Phase C: U1 = C1*X4 (regs), X8 = X4*X4 -> sF
  float u1[4] = {0.f,0.f,0.f,0.f};
  {
    float x8[4] = {0.f,0.f,0.f,0.f};
    mm4(sB1, sX4, r0, c0, u1);
    mm4(sX4, sX4, r0, c0, x8);
    #pragma unroll
    for (int m = 0; m < 4; ++m) sF[r0*LS + c0 + m] = x8[m];
  }
  __syncthreads();

  // Phase D: U2 = C2*X8; E = I + Xs + X2s/2 + X3s/6 + U1 + U2
  {
    float u2[4] = {0.f,0.f,0.f,0.f};
    mm4(sB2, sF, r0, c0, u2);
    #pragma unroll
    for (int m = 0; m < 4; ++m) {
      const float dlt = (r0 == c0 + m) ? 1.f : 0.f;
      const float xo  = sX[r0*LS + c0 + m]*sc1;
      const float x2o = sX2[r0*LS + c0 + m];
      sE[r0*LS + c0 + m] = dlt + xo + 0.5f*x2o + (1.f/6.f)*x3[m] + u1[m] + u2[m];
    }
  }
  __syncthreads();

  // squarings: E <- E*E, s times (ping-pong sE <-> sF)
  float* pe = sE;
  float* po = sF;
  for (int t = 0; t < s; ++t) {
    float acc[4] = {0.f,0.f,0.f,0.f};
    mm4(pe, pe, r0, c0, acc);
    #pragma unroll
    for (int m = 0; m < 4; ++m) po[r0*LS + c0 + m] = acc[m];
    __syncthreads();
    float* tp = pe; pe = po; po = tp;
  }

  // ---- phase: register Cholesky+subst (lanes 0..31) || ME = M*E (tids 64..191) ----
  if (tid < 32) {
    const int i = tid;
    float row[KD], Lr[KD];
    #pragma unroll
    for (int q4 = 0; q4 < KD; q4 += 4) {
      const float4 m4 = *(const float4*)&sM[i*LS + q4];
      row[q4+0] = m4.x; row[q4+1] = m4.y; row[q4+2] = m4.z; row[q4+3] = m4.w;
    }
    #pragma unroll
    for (int q = 0; q < KD; ++q) Lr[q] = 0.f;
    float dprod = 1.f;
    #pragma unroll
    for (int j = 0; j < KD; ++j) {
      const float djj = __shfl(row[j], j);
      const float d = sqrtf(djj);
      dprod *= d;
      const float lij = row[j] / d;          // valid for i >= j
      if (i >= j) Lr[j] = lij;
      #pragma unroll
      for (int q = j+1; q < KD; ++q)
        row[q] -= lij * __shfl(lij, q);
    }
    if (i == 0) g_ld[g] = 2.f * logf(dprod);

    // forward substitution: W[:,i] = L^-1 * E[:,i]
    float e[KD], w[KD];
    #pragma unroll
    for (int r = 0; r < KD; ++r) e[r] = pe[r*LS + i];
    #pragma unroll
    for (int r = 0; r < KD; ++r) {
      float acc = e[r];
      #pragma unroll
      for (int q = 0; q < r; ++q) acc -= __shfl(Lr[q], r) * w[q];
      w[r] = acc / __shfl(Lr[r], r);
    }
    #pragma unroll
    for (int r = 0; r < KD; ++r) sW[r*LS + i] = w[r];
    // v = E^T mu
    float vacc = 0.f;
    #pragma unroll
    for (int r = 0; r < KD; ++r) vacc += e[r] * mu_q[g*KD + r];
    g_v[g*KD + i] = vacc;
  } else if (tid >= 64 && tid < 192) {
    // ME = M * E -> sB2 (8 outputs per thread)
    const int t8 = (tid - 64) * 8;
    const int rm = t8 >> 5, cm = t8 & 31;
    float a[8] = {0.f,0.f,0.f,0.f,0.f,0.f,0.f,0.f};
    #pragma unroll
    for (int q4 = 0; q4 < KD; q4 += 4) {
      const float4 a4 = *(const float4*)&sM[rm*LS + q4];
      const float ar[4] = {a4.x, a4.y, a4.z, a4.w};
      #pragma unroll
      for (int u = 0; u < 4; ++u) {
        const float4 b0 = *(const float4*)&pe[(q4+u)*LS + cm];
        const float4 b1 = *(const float4*)&pe[(q4+u)*LS + cm + 4];
        a[0] += ar[u]*b0.x; a[1] += ar[u]*b0.y; a[2] += ar[u]*b0.z; a[3] += ar[u]*b0.w;
        a[4] += ar[u]*b1.x; a[5] += ar[u]*b1.y; a[6] += ar[u]*b1.z; a[7] += ar[u]*b1.w;
      }
    }
    #pragma unroll
    for (int m = 0; m < 8; ++m) sB2[rm*LS + cm + m] = a[m];
  }
  __syncthreads();

  // ---- final phase: Q = W^T W, T = E^T (ME), export E ----
  {
    float aq[4] = {0.f,0.f,0.f,0.f}, at[4] = {0.f,0.f,0.f,0.f};
    #pragma unroll
    for (int q = 0; q < KD; ++q) {
      const float wq = sW[q*LS + r0];
      const float eq = pe[q*LS + r0];
      const float4 wb = *(const float4*)&sW[q*LS + c0];
      const float4 mb = *(const float4*)&sB2[q*LS + c0];
      aq[0] += wq*wb.x; aq[1] += wq*wb.y; aq[2] += wq*wb.z; aq[3] += wq*wb.w;
      at[0] += eq*mb.x; at[1] += eq*mb.y; at[2] += eq*mb.z; at[3] += eq*mb.w;
    }
    const float4 ev = *(const float4*)&pe[r0*LS + c0];
    *(float4*)&g_Q[(size_t)g*1024 + r0*KD + c0] = make_float4(aq[0],aq[1],aq[2],aq[3]);
    *(float4*)&g_T[(size_t)g*1024 + r0*KD + c0] = make_float4(at[0],at[1],at[2],at[3]);
    *(float4*)&g_E[(size_t)g*1024 + r0*KD + c0] = ev;
  }
}

// ---------------- Kernel 2: pairwise KL + softmax + aggregate ----------------
__device__ __forceinline__ float d4(float4 a, float4 b) {
  return a.x*b.x + a.y*b.y + a.z*b.z + a.w*b.w;
}

__global__ __launch_bounds__(256) void pair_kernel(float* __restrict__ out) {
  const int g = blockIdx.x;
  const int b = g >> 7;
  const int i = g & (NA - 1);
  const int tid = threadIdx.x;
  __shared__ __align__(16) float sv[NA*KD];   // 16 KB
  __shared__ float sld[NA];
  __shared__ float skl[NA];
  __shared__ float sbeta[NA];
  __shared__ float spart[8*KD];
  __shared__ float sw[KD];

  {
    const float4* vs = (const float4*)(g_v + (size_t)b*NA*KD);
    float4* dv = (float4*)sv;
    #pragma unroll
    for (int m = 0; m < 4; ++m) dv[tid + 256*m] = vs[tid + 256*m];
    if (tid < NA) sld[tid] = g_ld[b*NA + tid];
  }

  const int lane = tid & 63;
  const int wave = tid >> 6;
  const int k  = lane >> 1;
  const int l0 = (lane & 1) * 16;

  // T_i row chunk in registers (lane-constant over the whole j loop)
  float4 t0, t1, t2, t3;
  {
    const float4* Tp = (const float4*)(g_T + (size_t)g*1024 + k*KD + l0);
    t0 = Tp[0]; t1 = Tp[1]; t2 = Tp[2]; t3 = Tp[3];
  }
  __syncthreads();

  float4 vi0, vi1, vi2, vi3;
  {
    const float4* vp = (const float4*)(sv + i*KD + l0);
    vi0 = vp[0]; vi1 = vp[1]; vi2 = vp[2]; vi3 = vp[3];
  }
  const float vik = sv[i*KD + k];
  const float ldi = sld[i];
  const float* Qb = g_Q + (size_t)b*NA*1024 + k*KD + l0;

  #pragma unroll 2
  for (int j = wave; j < NA; j += 4) {
    const float4* Qp = (const float4*)(Qb + (size_t)j*1024);
    const float4 q0 = Qp[0], q1 = Qp[1], q2 = Qp[2], q3 = Qp[3];
    const float4* vj = (const float4*)(sv + j*KD + l0);
    const float4 w0 = vj[0], w1 = vj[1], w2 = vj[2], w3 = vj[3];
    const float dk = sv[j*KD + k] - vik;
    float tr = d4(q0,t0) + d4(q1,t1) + d4(q2,t2) + d4(q3,t3);
    const float4 e0 = make_float4(w0.x-vi0.x, w0.y-vi0.y, w0.z-vi0.z, w0.w-vi0.w);
    const float4 e1 = make_float4(w1.x-vi1.x, w1.y-vi1.y, w1.z-vi1.z, w1.w-vi1.w);
    const float4 e2 = make_float4(w2.x-vi2.x, w2.y-vi2.y, w2.z-vi2.z, w2.w-vi2.w);
    const float4 e3 = make_float4(w3.x-vi3.x, w3.y-vi3.y, w3.z-vi3.z, w3.w-vi3.w);
    float qd = (d4(q0,e0) + d4(q1,e1) + d4(q2,e2) + d4(q3,e3)) * dk;
    #pragma unroll
    for (int o = 1; o < 64; o <<= 1) {
      tr += __shfl_xor(tr, o);
      qd += __shfl_xor(qd, o);
    }
    if (lane == 0)
      skl[j] = fmaxf(0.5f*(tr + qd - (float)KD + sld[j] - ldi), 0.f);
  }
  __syncthreads();

  // softmax over j in one wave: lane holds kl[lane], kl[lane+64]
  if (tid < 64) {
    const float a = skl[tid], c = skl[tid + 64];
    float mn = fminf(a, c);              // max of -kl = -min kl
    #pragma unroll
    for (int o = 1; o < 64; o <<= 1) mn = fminf(mn, __shfl_xor(mn, o));
    const float ea = expf(mn - a);
    const float eb = expf(mn - c);
    float sm = ea + eb;
    #pragma unroll
    for (int o = 1; o < 64; o <<= 1) sm += __shfl_xor(sm, o);
    const float inv = 1.f / sm;
    const float ren = 1.0f / (1.0f + 128.0f * 1e-8f);
    sbeta[tid]      = (ea*inv + 1e-8f) * ren;
    sbeta[tid + 64] = (eb*inv + 1e-8f) * ren;
  }
  __syncthreads();

  // w = sum_j beta_j v_j (8 chunks x 32 components), then out = E_i * w
  {
    const int c = tid >> 5, kk = tid & 31;
    float acc = 0.f;
    #pragma unroll
    for (int jj = 0; jj < 16; ++jj) {
      const int j = c*16 + jj;
      acc += sbeta[j] * sv[j*KD + kk];
    }
    spart[c*KD + kk] = acc;
  }
  __syncthreads();
  if (tid < KD) {
    float w = 0.f;
    #pragma unroll
    for (int c2 = 0; c2 < 8; ++c2) w += spart[c2*KD + tid];
    sw[tid] = w;
  }
  __syncthreads();
  if (tid < KD) {
    const float* Ei = g_E + (size_t)g*1024 + tid*KD;
    float acc = 0.f;
    #pragma unroll
    for (int l = 0; l < KD; ++l) acc += Ei[l] * sw[l];
    out[g*KD + tid] = acc;
  }
}

extern "C" void kernel_launch(void* const* d_in, const int* in_sizes, int n_in,
                              void* d_out, int out_size, void* d_ws, size_t ws_size,
                              hipStream_t stream) {
  (void)in_sizes; (void)n_in; (void)out_size; (void)d_ws; (void)ws_size;
  const float* mu_q    = (const float*)d_in[0];
  const float* sigma_q = (const float*)d_in[1];
  const float* phi     = (const float*)d_in[2];
  const float* gen     = (const float*)d_in[3];
  float* out = (float*)d_out;
  hipLaunchKernelGGL(agent_kernel, dim3(BN), dim3(256), 0, stream,
                     mu_q, sigma_q, phi, gen);
  hipLaunchKernelGGL(pair_kernel, dim3(BN), dim3(256), 0, stream, out);
}

// Round 3
// 95.878 us; speedup vs baseline: 1.6523x; 1.1866x over previous
//
#include <hip/hip_runtime.h>
#include <math.h>

#define NB 2
#define NA 128
#define KD 32
#define LS 36            // LDS row stride: 16B-aligned float4s, conflict-free
#define BN (NB*NA)       // 256 agents total
#define EPSV 1e-8f

// Static device scratch (graph-capture-safe; fully rewritten every launch).
__device__ __align__(16) float g_Q[BN*KD*KD];   // E^T (Sig+eps)^-1 E
__device__ __align__(16) float g_T[BN*KD*KD];   // E^T (Sig+eps) E
__device__ __align__(16) float g_E[BN*KD*KD];   // expm(X)
__device__ __align__(16) float g_v[BN*KD];      // E^T mu
__device__ __align__(16) float g_ld[BN];        // logdet(Sig+eps)

__device__ __forceinline__ float rdlane(float x, int l) {
  return __int_as_float(__builtin_amdgcn_readlane(__float_as_int(x), l));
}

// acc[m] += sum_q A[r0][q] * B[q][c0+m]   (32x32, LS-strided LDS tiles)
__device__ __forceinline__ void mm4(const float* A, const float* B,
                                    int r0, int c0, float acc[4]) {
  #pragma unroll
  for (int q4 = 0; q4 < KD; q4 += 4) {
    const float4 a4 = *(const float4*)&A[r0*LS + q4];
    const float ar[4] = {a4.x, a4.y, a4.z, a4.w};
    #pragma unroll
    for (int u = 0; u < 4; ++u) {
      const float4 b4 = *(const float4*)&B[(q4+u)*LS + c0];
      acc[0] += ar[u]*b4.x; acc[1] += ar[u]*b4.y;
      acc[2] += ar[u]*b4.z; acc[3] += ar[u]*b4.w;
    }
  }
}

// ---------------- Kernel 1: per-agent factorizations ----------------
__global__ __launch_bounds__(256, 1) void agent_kernel(
    const float* __restrict__ mu_q, const float* __restrict__ sigma_q,
    const float* __restrict__ phi, const float* __restrict__ gen) {
  const int g = blockIdx.x;
  const int tid = threadIdx.x;
  __shared__ __align__(16) float sM[KD*LS];
  __shared__ __align__(16) float sX[KD*LS];   // unscaled X
  __shared__ __align__(16) float sX2[KD*LS];  // (Xs)^2
  __shared__ __align__(16) float sX4[KD*LS];  // (Xs)^4
  __shared__ __align__(16) float sB1[KD*LS];  // C1(Xs), later scratch
  __shared__ __align__(16) float sB2[KD*LS];  // C2(Xs), later ME
  __shared__ __align__(16) float sE[KD*LS];
  __shared__ __align__(16) float sF[KD*LS];   // X8, then squaring ping-pong
  __shared__ __align__(16) float sW[KD*LS];   // W = L^-1 E
  __shared__ float smu[KD];
  __shared__ float snrm;

  const int e0 = tid * 4;
  const int r0 = e0 >> 5;
  const int c0 = e0 & 31;

  // ---- build X (unscaled) + M, Frobenius norm ----
  const float p0 = phi[g*3+0], p1 = phi[g*3+1], p2 = phi[g*3+2];
  if (tid == 0) snrm = 0.f;
  if (tid < KD) smu[tid] = mu_q[g*KD + tid];
  float nrm = 0.f;
  {
    const float* g0p = gen + e0;
    const float* g1p = gen + 1024 + e0;
    const float* g2p = gen + 2048 + e0;
    const float4 sg = *(const float4*)(sigma_q + (size_t)g*1024 + e0);
    const float sgv[4] = {sg.x, sg.y, sg.z, sg.w};
    #pragma unroll
    for (int m = 0; m < 4; ++m) {
      const float x = p0*g0p[m] + p1*g1p[m] + p2*g2p[m];
      sX[r0*LS + c0 + m] = x;
      nrm += x*x;
      sM[r0*LS + c0 + m] = sgv[m] + ((r0 == c0 + m) ? EPSV : 0.f);
    }
  }
  __syncthreads();                       // snrm init + LDS visible
  #pragma unroll
  for (int o = 1; o < 64; o <<= 1) nrm += __shfl_xor(nrm, o);
  if ((tid & 63) == 0) atomicAdd(&snrm, nrm);
  __syncthreads();

  const float anorm = sqrtf(snrm);
  int s = 0;
  if (anorm > 1.f) { s = (int)ceilf(log2f(anorm)); s = min(s, 15); }
  const float sc1 = exp2f((float)(-s));  // Xs = sc1 * X
  const float sc2 = sc1*sc1;

  // Taylor coeffs 1/k!
  const float C4 = 1.f/24.f,    C5 = 1.f/120.f,     C6 = 1.f/720.f,     C7 = 1.f/5040.f;
  const float C8 = 1.f/40320.f, C9 = 1.f/362880.f, C10 = 1.f/3628800.f, C11 = 1.f/39916800.f;

  // Phase A: X2s = sc2 * (Xu*Xu)
  {
    float a2[4] = {0.f,0.f,0.f,0.f};
    mm4(sX, sX, r0, c0, a2);
    #pragma unroll
    for (int m = 0; m < 4; ++m) sX2[r0*LS + c0 + m] = a2[m]*sc2;
  }
  __syncthreads();

  // Phase B: X3s = sc1*(X2s*Xu), X4s = X2s*X2s; fold C1/C2 elementwise
  float x3[4];
  {
    float a3[4] = {0.f,0.f,0.f,0.f}, a4[4] = {0.f,0.f,0.f,0.f};
    mm4(sX2, sX, r0, c0, a3);
    mm4(sX2, sX2, r0, c0, a4);
    #pragma unroll
    for (int m = 0; m < 4; ++m) {
      x3[m] = a3[m]*sc1;
      const float dlt = (r0 == c0 + m) ? 1.f : 0.f;
      const float xo  = sX[r0*LS + c0 + m]*sc1;  // Xs element
      const float x2o = sX2[r0*LS + c0 + m];
      sX4[r0*LS + c0 + m] = a4[m];
      sB1[r0*LS + c0 + m] = C4*dlt + C5*xo + C6*x2o + C7*x3[m];
      sB2[r0*LS + c0 + m] = C8*dlt + C9*xo + C10*x2o + C11*x3[m];
    }
  }
  __syncthreads();

  // Phase C: U1 = C1*X4 (regs), X8 = X4*X4 -> sF
  float u1[4] = {0.f,0.f,0.f,0.f};
  {
    float x8[4] = {0.f,0.f,0.f,0.f};
    mm4(sB1, sX4, r0, c0, u1);
    mm4(sX4, sX4, r0, c0, x8);
    #pragma unroll
    for (int m = 0; m < 4; ++m) sF[r0*LS + c0 + m] = x8[m];
  }
  __syncthreads();

  // Phase D: U2 = C2*X8; E = I + Xs + X2s/2 + X3s/6 + U1 + U2
  {
    float u2[4] = {0.f,0.f,0.f,0.f};
    mm4(sB2, sF, r0, c0, u2);
    #pragma unroll
    for (int m = 0; m < 4; ++m) {
      const float dlt = (r0 == c0 + m) ? 1.f : 0.f;
      const float xo  = sX[r0*LS + c0 + m]*sc1;
      const float x2o = sX2[r0*LS + c0 + m];
      sE[r0*LS + c0 + m] = dlt + xo + 0.5f*x2o + (1.f/6.f)*x3[m] + u1[m] + u2[m];
    }
  }
  __syncthreads();

  // squarings: E <- E*E, s times (ping-pong sE <-> sF)
  float* pe = sE;
  float* po = sF;
  for (int t = 0; t < s; ++t) {
    float acc[4] = {0.f,0.f,0.f,0.f};
    mm4(pe, pe, r0, c0, acc);
    #pragma unroll
    for (int m = 0; m < 4; ++m) po[r0*LS + c0 + m] = acc[m];
    __syncthreads();
    float* tp = pe; pe = po; po = tp;
  }

  // ---- phase: readlane Cholesky + parallel substitution (wave 0)
  //            || v = E^T mu (wave 1) || ME = M*E (waves 2-3) ----
  if (tid < 64) {
    const int i = tid & 31;
    // prefetch E column i (substitution RHS) to hide conflicted LDS reads
    float acc[KD];
    #pragma unroll
    for (int r = 0; r < KD; ++r) acc[r] = pe[r*LS + i];
    // load M row i
    float row[KD];
    #pragma unroll
    for (int q4 = 0; q4 < KD; q4 += 4) {
      const float4 m4 = *(const float4*)&sM[i*LS + q4];
      row[q4+0] = m4.x; row[q4+1] = m4.y; row[q4+2] = m4.z; row[q4+3] = m4.w;
    }
    float Lr[KD], dinv[KD];
    float dprod = 1.f;
    #pragma unroll
    for (int j = 0; j < KD; ++j) {
      const float djj = rdlane(row[j], j);     // lane j's updated diagonal
      const float d = sqrtf(djj);
      const float rin = 1.f / d;
      dprod *= d;
      dinv[j] = rin;
      const float lij = row[j] * rin;          // valid for lanes i >= j
      Lr[j] = lij;
      #pragma unroll
      for (int q = j + 1; q < KD; ++q)
        row[q] = fmaf(-lij, rdlane(lij, q), row[q]);
    }
    if (tid == 0) g_ld[g] = 2.f * logf(dprod);

    // right-looking forward substitution: W[:,i] = L^-1 E[:,i]
    #pragma unroll
    for (int q = 0; q < KD; ++q) {
      const float wq = acc[q] * dinv[q];
      acc[q] = wq;
      #pragma unroll
      for (int r = q + 1; r < KD; ++r)
        acc[r] = fmaf(-rdlane(Lr[q], r), wq, acc[r]);
    }
    #pragma unroll
    for (int r = 0; r < KD; ++r) sW[r*LS + i] = acc[r];
  } else if (tid < 128) {
    const int c = tid - 64;
    if (c < KD) {                               // v = E^T mu
      float va = 0.f;
      #pragma unroll
      for (int r = 0; r < KD; ++r) va += pe[r*LS + c] * smu[r];
      g_v[g*KD + c] = va;
    }
  } else {
    // ME = M * E -> sB2 (threads 128..255, 8 outputs each)
    const int t8 = (tid - 128) * 8;
    const int rm = t8 >> 5, cm = t8 & 31;
    float a[8] = {0.f,0.f,0.f,0.f,0.f,0.f,0.f,0.f};
    #pragma unroll
    for (int q4 = 0; q4 < KD; q4 += 4) {
      const float4 a4 = *(const float4*)&sM[rm*LS + q4];
      const float ar[4] = {a4.x, a4.y, a4.z, a4.w};
      #pragma unroll
      for (int u = 0; u < 4; ++u) {
        const float4 b0 = *(const float4*)&pe[(q4+u)*LS + cm];
        const float4 b1 = *(const float4*)&pe[(q4+u)*LS + cm + 4];
        a[0] += ar[u]*b0.x; a[1] += ar[u]*b0.y; a[2] += ar[u]*b0.z; a[3] += ar[u]*b0.w;
        a[4] += ar[u]*b1.x; a[5] += ar[u]*b1.y; a[6] += ar[u]*b1.z; a[7] += ar[u]*b1.w;
      }
    }
    #pragma unroll
    for (int m = 0; m < 8; ++m) sB2[rm*LS + cm + m] = a[m];
  }
  __syncthreads();

  // ---- final phase: Q = W^T W, T = E^T (ME), export E ----
  {
    float aq[4] = {0.f,0.f,0.f,0.f}, at[4] = {0.f,0.f,0.f,0.f};
    #pragma unroll
    for (int q = 0; q < KD; ++q) {
      const float wq = sW[q*LS + r0];
      const float eq = pe[q*LS + r0];
      const float4 wb = *(const float4*)&sW[q*LS + c0];
      const float4 mb = *(const float4*)&sB2[q*LS + c0];
      aq[0] += wq*wb.x; aq[1] += wq*wb.y; aq[2] += wq*wb.z; aq[3] += wq*wb.w;
      at[0] += eq*mb.x; at[1] += eq*mb.y; at[2] += eq*mb.z; at[3] += eq*mb.w;
    }
    const float4 ev = *(const float4*)&pe[r0*LS + c0];
    *(float4*)&g_Q[(size_t)g*1024 + r0*KD + c0] = make_float4(aq[0],aq[1],aq[2],aq[3]);
    *(float4*)&g_T[(size_t)g*1024 + r0*KD + c0] = make_float4(at[0],at[1],at[2],at[3]);
    *(float4*)&g_E[(size_t)g*1024 + r0*KD + c0] = ev;
  }
}

// ---------------- Kernel 2: pairwise KL + softmax + aggregate ----------------
__device__ __forceinline__ float d4(float4 a, float4 b) {
  return a.x*b.x + a.y*b.y + a.z*b.z + a.w*b.w;
}

__global__ __launch_bounds__(512, 1) void pair_kernel(float* __restrict__ out) {
  const int g = blockIdx.x;
  const int b = g >> 7;
  const int i = g & (NA - 1);
  const int tid = threadIdx.x;
  __shared__ __align__(16) float sv[NA*KD];   // 16 KB
  __shared__ float sld[NA];
  __shared__ float skl[NA];
  __shared__ float sbeta[NA];
  __shared__ float spart[16*KD];
  __shared__ float sw[KD];

  {
    const float4* vs = (const float4*)(g_v + (size_t)b*NA*KD);
    float4* dv = (float4*)sv;
    dv[tid] = vs[tid];
    dv[tid + 512] = vs[tid + 512];
    if (tid < NA) sld[tid] = g_ld[b*NA + tid];
  }

  const int lane = tid & 63;
  const int wave = tid >> 6;
  const int k  = lane >> 1;
  const int l0 = (lane & 1) * 16;

  // T_i row chunk in registers (lane-constant over the whole j loop)
  float4 t0, t1, t2, t3;
  {
    const float4* Tp = (const float4*)(g_T + (size_t)g*1024 + k*KD + l0);
    t0 = Tp[0]; t1 = Tp[1]; t2 = Tp[2]; t3 = Tp[3];
  }
  __syncthreads();

  float4 vi0, vi1, vi2, vi3;
  {
    const float4* vp = (const float4*)(sv + i*KD + l0);
    vi0 = vp[0]; vi1 = vp[1]; vi2 = vp[2]; vi3 = vp[3];
  }
  const float vik = sv[i*KD + k];
  const float ldi = sld[i];
  const float* Qb = g_Q + (size_t)b*NA*1024 + k*KD + l0;

  #pragma unroll 2
  for (int j = wave; j < NA; j += 8) {
    const float4* Qp = (const float4*)(Qb + (size_t)j*1024);
    const float4 q0 = Qp[0], q1 = Qp[1], q2 = Qp[2], q3 = Qp[3];
    const float4* vj = (const float4*)(sv + j*KD + l0);
    const float4 w0 = vj[0], w1 = vj[1], w2 = vj[2], w3 = vj[3];
    const float dk = sv[j*KD + k] - vik;
    const float4 e0 = make_float4(w0.x-vi0.x, w0.y-vi0.y, w0.z-vi0.z, w0.w-vi0.w);
    const float4 e1 = make_float4(w1.x-vi1.x, w1.y-vi1.y, w1.z-vi1.z, w1.w-vi1.w);
    const float4 e2 = make_float4(w2.x-vi2.x, w2.y-vi2.y, w2.z-vi2.z, w2.w-vi2.w);
    const float4 e3 = make_float4(w3.x-vi3.x, w3.y-vi3.y, w3.z-vi3.z, w3.w-vi3.w);
    float sacc = d4(q0,t0) + d4(q1,t1) + d4(q2,t2) + d4(q3,t3)
               + (d4(q0,e0) + d4(q1,e1) + d4(q2,e2) + d4(q3,e3)) * dk;
    #pragma unroll
    for (int o = 1; o < 64; o <<= 1) sacc += __shfl_xor(sacc, o);
    if (lane == 0)
      skl[j] = fmaxf(0.5f*(sacc - (float)KD + sld[j] - ldi), 0.f);
  }
  __syncthreads();

  // softmax over j in one wave: lane holds kl[lane], kl[lane+64]
  if (tid < 64) {
    const float a = skl[tid], c = skl[tid + 64];
    float mn = fminf(a, c);              // max of -kl = -min kl
    #pragma unroll
    for (int o = 1; o < 64; o <<= 1) mn = fminf(mn, __shfl_xor(mn, o));
    const float ea = expf(mn - a);
    const float eb = expf(mn - c);
    float sm = ea + eb;
    #pragma unroll
    for (int o = 1; o < 64; o <<= 1) sm += __shfl_xor(sm, o);
    const float inv = 1.f / sm;
    const float ren = 1.0f / (1.0f + 128.0f * 1e-8f);
    sbeta[tid]      = (ea*inv + 1e-8f) * ren;
    sbeta[tid + 64] = (eb*inv + 1e-8f) * ren;
  }
  __syncthreads();

  // w = sum_j beta_j v_j (16 chunks x 32 components), then out = E_i * w
  {
    const int c = tid >> 5, kk = tid & 31;
    float acc = 0.f;
    #pragma unroll
    for (int jj = 0; jj < 8; ++jj) {
      const int j = c*8 + jj;
      acc += sbeta[j] * sv[j*KD + kk];
    }
    spart[c*KD + kk] = acc;
  }
  __syncthreads();
  if (tid < KD) {
    float w = 0.f;
    #pragma unroll
    for (int c2 = 0; c2 < 16; ++c2) w += spart[c2*KD + tid];
    sw[tid] = w;
  }
  __syncthreads();
  if (tid < KD) {
    const float* Ei = g_E + (size_t)g*1024 + tid*KD;
    float acc = 0.f;
    #pragma unroll
    for (int l = 0; l < KD; ++l) acc += Ei[l] * sw[l];
    out[g*KD + tid] = acc;
  }
}

extern "C" void kernel_launch(void* const* d_in, const int* in_sizes, int n_in,
                              void* d_out, int out_size, void* d_ws, size_t ws_size,
                              hipStream_t stream) {
  (void)in_sizes; (void)n_in; (void)out_size; (void)d_ws; (void)ws_size;
  const float* mu_q    = (const float*)d_in[0];
  const float* sigma_q = (const float*)d_in[1];
  const float* phi     = (const float*)d_in[2];
  const float* gen     = (const float*)d_in[3];
  float* out = (float*)d_out;
  hipLaunchKernelGGL(agent_kernel, dim3(BN), dim3(256), 0, stream,
                     mu_q, sigma_q, phi, gen);
  hipLaunchKernelGGL(pair_kernel, dim3(BN), dim3(512), 0, stream, out);
}